// Round 1
// baseline (329.714 us; speedup 1.0000x reference)
//
#include <hip/hip_runtime.h>
#include <stdint.h>

#define L_SEQ 256
#define E_DIM 64
#define N_B   64
#define LN_EPS 1e-5f

typedef float f4 __attribute__((ext_vector_type(4)));

// ---------------------------------------------------------------------------
// K1: one block per n (grid 64 x 256 threads, 128 KB LDS).
// Fully fused per-n pipeline producing the h-independent LN row tensor
// M[n][l][e] (4 MB) into ws:
//   energy[a,b] = sum_l Q[n,l,a]*K[n,l,b] ; attn = softmax over b (hd==1)
//   P[k][e]  = sum_q attn[q][k] * W_out[e][q]          (64^3 tiny GEMM)
//   fc[l][e] = sum_k values[k,l,n] * P[k][e] + b[e]    (associativity-
//              reordered: avoids the 256x64 out2 intermediate entirely)
//   M[l][e]  = LN_e(fc[l][:])   (+query residual is const over e -> cancels)
// LDS: phase 1 holds Q,K tiles (128 KB); phase 2 reuses the same memory for
// Vn (64 KB) + attn/Wt/P (16 KB each).
// ---------------------------------------------------------------------------
__global__ __launch_bounds__(256) void fused_row_kernel(
    const float* __restrict__ gq,
    const float* __restrict__ gk,
    const float* __restrict__ gv,
    const float* __restrict__ gw,
    const float* __restrict__ gbo,
    const float* __restrict__ glnw,
    const float* __restrict__ glnb,
    float*       __restrict__ ws)
{
    __shared__ float lds[32768];          // 128 KB
    float* Qs    = lds;                   // phase1: [l][a], 16384 floats
    float* Ks    = lds + 16384;           // phase1: [l][b], 16384 floats
    float* VnS   = lds;                   // phase2: [k][l], 16384 (over Qs)
    float* attnS = lds + 16384;           // phase2: [q][k], 4096  (over Ks)
    float* WtS   = lds + 20480;           // phase2: [q][e], 4096
    float* PS    = lds + 24576;           // phase2: [k][e], 4096

    const int t = threadIdx.x;
    const int n = blockIdx.x;
    const float* qb = gq + (size_t)n * (L_SEQ * E_DIM);
    const float* kb = gk + (size_t)n * (L_SEQ * E_DIM);

    // ---- stage Q,K (coalesced f4) ----
    #pragma unroll
    for (int i = 0; i < 16; ++i) {
        reinterpret_cast<f4*>(Qs)[t + 256 * i] =
            reinterpret_cast<const f4*>(qb)[t + 256 * i];
        reinterpret_cast<f4*>(Ks)[t + 256 * i] =
            reinterpret_cast<const f4*>(kb)[t + 256 * i];
    }
    __syncthreads();

    const int tx = t & 15, ty = t >> 4;
    const int b0 = tx * 4, a0 = ty * 4;

    // ---- energy: 4x4 tile per thread ----
    float acc[4][4] = {};
    #pragma unroll 8
    for (int l = 0; l < L_SEQ; ++l) {
        f4 qa = *reinterpret_cast<const f4*>(&Qs[l * E_DIM + a0]);
        f4 kv = *reinterpret_cast<const f4*>(&Ks[l * E_DIM + b0]);
        #pragma unroll
        for (int ia = 0; ia < 4; ++ia)
            #pragma unroll
            for (int ib = 0; ib < 4; ++ib)
                acc[ia][ib] = fmaf(qa[ia], kv[ib], acc[ia][ib]);
    }

    // ---- softmax over b; row a0+ia spread over the 16 tx lanes ----
    #pragma unroll
    for (int ia = 0; ia < 4; ++ia) {
        float m = fmaxf(fmaxf(acc[ia][0], acc[ia][1]),
                        fmaxf(acc[ia][2], acc[ia][3]));
        #pragma unroll
        for (int s = 1; s <= 8; s <<= 1) m = fmaxf(m, __shfl_xor(m, s));
        float e0v = __expf(acc[ia][0] - m);
        float e1v = __expf(acc[ia][1] - m);
        float e2v = __expf(acc[ia][2] - m);
        float e3v = __expf(acc[ia][3] - m);
        float ssum = (e0v + e1v) + (e2v + e3v);
        #pragma unroll
        for (int s = 1; s <= 8; s <<= 1) ssum += __shfl_xor(ssum, s);
        float inv = 1.0f / ssum;
        acc[ia][0] = e0v * inv; acc[ia][1] = e1v * inv;
        acc[ia][2] = e2v * inv; acc[ia][3] = e3v * inv;
    }

    __syncthreads();   // everyone done reading Qs/Ks before reuse

    // ---- store attn rows [q][k] (f4 row writes) ----
    #pragma unroll
    for (int ia = 0; ia < 4; ++ia) {
        f4 v4 = {acc[ia][0], acc[ia][1], acc[ia][2], acc[ia][3]};
        *reinterpret_cast<f4*>(&attnS[(a0 + ia) * 64 + b0]) = v4;
    }

    // ---- stage WtS[q][e] = W_out[e][q] (coalesced global read) ----
    #pragma unroll
    for (int i = 0; i < 16; ++i) {
        int idx = t + 256 * i;            // = e*64 + q
        WtS[(idx & 63) * 64 + (idx >> 6)] = gw[idx];
    }

    // ---- stage VnS[k][l] = values[k,l,n] (stride-256B scalar loads) ----
    #pragma unroll
    for (int k = 0; k < 64; ++k)
        VnS[k * 256 + t] = gv[((size_t)k * 256 + (size_t)t) * 64 + n];

    __syncthreads();

    // ---- P[k][e] = sum_q attn[q][k] * Wt[q][e]; 4k x 4e per thread ----
    const int k0 = ty * 4, e0 = tx * 4;
    float pacc[4][4] = {};
    #pragma unroll 8
    for (int q = 0; q < 64; ++q) {
        f4 av = *reinterpret_cast<const f4*>(&attnS[q * 64 + k0]);
        f4 wv = *reinterpret_cast<const f4*>(&WtS[q * 64 + e0]);
        #pragma unroll
        for (int ik = 0; ik < 4; ++ik)
            #pragma unroll
            for (int ie = 0; ie < 4; ++ie)
                pacc[ik][ie] = fmaf(av[ik], wv[ie], pacc[ik][ie]);
    }
    #pragma unroll
    for (int ik = 0; ik < 4; ++ik) {
        f4 v4 = {pacc[ik][0], pacc[ik][1], pacc[ik][2], pacc[ik][3]};
        *reinterpret_cast<f4*>(&PS[(k0 + ik) * 64 + e0]) = v4;
    }

    // param vectors for this thread's e-slice (overlap latency with barrier)
    f4 be = *reinterpret_cast<const f4*>(&gbo[e0]);
    f4 lw = *reinterpret_cast<const f4*>(&glnw[e0]);
    f4 lb = *reinterpret_cast<const f4*>(&glnb[e0]);

    __syncthreads();

    // ---- fc[l][e] = sum_k Vn[k][l]*P[k][e]; 16l x 4e per thread ----
    const int l0 = ty * 16;
    float fcv[16][4] = {};
    #pragma unroll 4
    for (int k = 0; k < 64; ++k) {
        f4 p4 = *reinterpret_cast<const f4*>(&PS[k * 64 + e0]);
        f4 vv[4];
        #pragma unroll
        for (int g = 0; g < 4; ++g)
            vv[g] = *reinterpret_cast<const f4*>(&VnS[k * 256 + l0 + 4 * g]);
        #pragma unroll
        for (int g = 0; g < 4; ++g)
            #pragma unroll
            for (int j = 0; j < 4; ++j)
                #pragma unroll
                for (int ie = 0; ie < 4; ++ie)
                    fcv[g * 4 + j][ie] = fmaf(vv[g][j], p4[ie], fcv[g * 4 + j][ie]);
    }

    // ---- LN per (n,l) row (spread over 16 tx lanes), store to ws ----
    float* wbase = ws + (size_t)n * 16384 + (size_t)l0 * 64 + e0;
    #pragma unroll
    for (int il = 0; il < 16; ++il) {
        float v0 = fcv[il][0] + be[0];
        float v1 = fcv[il][1] + be[1];
        float v2 = fcv[il][2] + be[2];
        float v3 = fcv[il][3] + be[3];
        float s1 = (v0 + v1) + (v2 + v3);
        float s2 = (v0 * v0 + v1 * v1) + (v2 * v2 + v3 * v3);
        #pragma unroll
        for (int s = 1; s <= 8; s <<= 1) {
            s1 += __shfl_xor(s1, s);
            s2 += __shfl_xor(s2, s);
        }
        float mu  = s1 * (1.0f / 64.0f);
        float var = s2 * (1.0f / 64.0f) - mu * mu;
        float rs  = rsqrtf(var + LN_EPS);
        f4 o;
        o[0] = (v0 - mu) * rs * lw[0] + lb[0];
        o[1] = (v1 - mu) * rs * lw[1] + lb[1];
        o[2] = (v2 - mu) * rs * lw[2] + lb[2];
        o[3] = (v3 - mu) * rs * lw[3] + lb[3];
        *reinterpret_cast<f4*>(wbase + (size_t)il * 64) = o;
    }
}

// ---------------------------------------------------------------------------
// K2: pure broadcast of the 4 MB row tensor to all 64 h slices (256 MiB).
// 1024 blocks x 256 threads (4 blocks/CU). Each thread: 1 f4 load, 64
// nontemporal f4 stores. Per wave store instr = 1 KB fully contiguous.
// Write-stream bound -> should track the ~6.4 TB/s fill-kernel ceiling.
// ---------------------------------------------------------------------------
__global__ __launch_bounds__(256) void bcast_kernel(
    const float* __restrict__ ws,
    float*       __restrict__ gout)
{
    const int t  = threadIdx.x;
    const int b  = blockIdx.x;
    const int n  = b >> 4;            // 64 n
    const int lc = b & 15;            // 16 l-chunks of 16 rows
    const int r  = t >> 4;            // row within chunk
    const int c  = t & 15;            // f4 within row

    const size_t row = (size_t)n * 16384 + (size_t)(lc * 16 + r) * 64
                     + (size_t)c * 4;
    f4 v = *reinterpret_cast<const f4*>(ws + row);

    float* op = gout + row;
    #pragma unroll
    for (int h = 0; h < 64; ++h) {
        __builtin_nontemporal_store(v, reinterpret_cast<f4*>(op));
        op += (size_t)N_B * L_SEQ * E_DIM;   // 1,048,576 floats = one h slice
    }
}

extern "C" void kernel_launch(void* const* d_in, const int* in_sizes, int n_in,
                              void* d_out, int out_size, void* d_ws, size_t ws_size,
                              hipStream_t stream)
{
    const float* gv  = (const float*)d_in[0];  // values  [N,L,E] f32
    const float* gk  = (const float*)d_in[1];  // keys    [N,L,E]
    const float* gq  = (const float*)d_in[2];  // query   [N,L,E]
    const float* gw  = (const float*)d_in[3];  // W_out   [E,E]
    const float* gbo = (const float*)d_in[4];  // b_out   [E]
    const float* glw = (const float*)d_in[5];  // ln_w    [E]
    const float* glb = (const float*)d_in[6];  // ln_b    [E]
    float* wsRow = (float*)d_ws;               // 64*256*64 f32 = 4 MiB scratch
    float* out   = (float*)d_out;              // [H,N,L,E] f32

    hipLaunchKernelGGL(fused_row_kernel, dim3(64), dim3(256), 0, stream,
                       gq, gk, gv, gw, gbo, glw, glb, wsRow);
    hipLaunchKernelGGL(bcast_kernel, dim3(1024), dim3(256), 0, stream,
                       wsRow, out);
}

// Round 2
// 311.418 us; speedup vs baseline: 1.0587x; 1.0587x over previous
//
#include <hip/hip_runtime.h>
#include <stdint.h>

#define L_SEQ 256
#define E_DIM 64
#define N_B   64
#define LN_EPS 1e-5f

typedef float f4 __attribute__((ext_vector_type(4)));
typedef float f2 __attribute__((ext_vector_type(2)));

// ---------------------------------------------------------------------------
// K1: one block per n (grid 64 x 512 threads = 2 waves/SIMD, 128 KB LDS).
//   energy[a,b] = sum_l Q[n,l,a]*K[n,l,b] ; attn = softmax over b (hd==1)
//   P[k][e]    = sum_q attn[q][k] * W_out[e][q]     (64^3 tiny GEMM)
//   ws[n][k][e] = P                                  (1 MB total)
// The heavy fc GEMM + LN + broadcast live in K2 on the full machine.
// ---------------------------------------------------------------------------
__global__ __launch_bounds__(512) void attn_p_kernel(
    const float* __restrict__ gq,
    const float* __restrict__ gk,
    const float* __restrict__ gw,
    float*       __restrict__ wsP)
{
    __shared__ float lds[32768];          // 128 KB
    float* Qs    = lds;                   // phase1: [l][a], 16384 floats
    float* Ks    = lds + 16384;           // phase1: [l][b], 16384 floats
    float* attnS = lds;                   // phase2: [q][k], 4096 (over Qs)
    float* WtS   = lds + 4096;            // phase2: [q][e] stride 68 (4352)

    const int t = threadIdx.x;
    const int n = blockIdx.x;
    const float* qb = gq + (size_t)n * (L_SEQ * E_DIM);
    const float* kb = gk + (size_t)n * (L_SEQ * E_DIM);

    // ---- stage Q,K (coalesced f4): 4096 f4 per tile, 8 per thread ----
    #pragma unroll
    for (int i = 0; i < 8; ++i) {
        reinterpret_cast<f4*>(Qs)[t + 512 * i] =
            reinterpret_cast<const f4*>(qb)[t + 512 * i];
        reinterpret_cast<f4*>(Ks)[t + 512 * i] =
            reinterpret_cast<const f4*>(kb)[t + 512 * i];
    }
    __syncthreads();

    const int tx = t & 15, ty = t >> 4;   // tx -> b-tile, ty (0..31) -> a-pair
    const int b0 = tx * 4, a0 = ty * 2;

    // ---- energy: 2x4 tile per thread (2048 FMA) ----
    float acc[2][4] = {};
    #pragma unroll 8
    for (int l = 0; l < L_SEQ; ++l) {
        f2 qa = *reinterpret_cast<const f2*>(&Qs[l * E_DIM + a0]);
        f4 kv = *reinterpret_cast<const f4*>(&Ks[l * E_DIM + b0]);
        #pragma unroll
        for (int ia = 0; ia < 2; ++ia)
            #pragma unroll
            for (int ib = 0; ib < 4; ++ib)
                acc[ia][ib] = fmaf(qa[ia], kv[ib], acc[ia][ib]);
    }

    // ---- softmax over b; row a0+ia spread over the 16 tx lanes ----
    #pragma unroll
    for (int ia = 0; ia < 2; ++ia) {
        float m = fmaxf(fmaxf(acc[ia][0], acc[ia][1]),
                        fmaxf(acc[ia][2], acc[ia][3]));
        #pragma unroll
        for (int s = 1; s <= 8; s <<= 1) m = fmaxf(m, __shfl_xor(m, s));
        float e0v = __expf(acc[ia][0] - m);
        float e1v = __expf(acc[ia][1] - m);
        float e2v = __expf(acc[ia][2] - m);
        float e3v = __expf(acc[ia][3] - m);
        float ssum = (e0v + e1v) + (e2v + e3v);
        #pragma unroll
        for (int s = 1; s <= 8; s <<= 1) ssum += __shfl_xor(ssum, s);
        float inv = 1.0f / ssum;
        acc[ia][0] = e0v * inv; acc[ia][1] = e1v * inv;
        acc[ia][2] = e2v * inv; acc[ia][3] = e3v * inv;
    }

    __syncthreads();   // all lanes done reading Qs/Ks before LDS reuse

    // ---- attnS[q][k] rows (f4), q = a0+ia ----
    #pragma unroll
    for (int ia = 0; ia < 2; ++ia) {
        f4 v4 = {acc[ia][0], acc[ia][1], acc[ia][2], acc[ia][3]};
        *reinterpret_cast<f4*>(&attnS[(a0 + ia) * 64 + b0]) = v4;
    }

    // ---- WtS[q][e] = W_out[e][q], stride 68 (write-conflict mitigated,
    //      rows still 16B-aligned for f4 reads) ----
    #pragma unroll
    for (int i = 0; i < 8; ++i) {
        int idx = t + 512 * i;            // = e*64 + q
        WtS[(idx & 63) * 68 + (idx >> 6)] = gw[idx];
    }
    __syncthreads();

    // ---- P[k][e] = sum_q attn[q][k] * Wt[q][e]; 2k x 4e per thread ----
    const int k0 = ty * 2, e0 = tx * 4;
    float pacc[2][4] = {};
    #pragma unroll 8
    for (int q = 0; q < 64; ++q) {
        f2 av = *reinterpret_cast<const f2*>(&attnS[q * 64 + k0]);
        f4 wv = *reinterpret_cast<const f4*>(&WtS[q * 68 + e0]);
        #pragma unroll
        for (int ik = 0; ik < 2; ++ik)
            #pragma unroll
            for (int ie = 0; ie < 4; ++ie)
                pacc[ik][ie] = fmaf(av[ik], wv[ie], pacc[ik][ie]);
    }
    float* pb = wsP + (size_t)n * 4096 + e0;
    #pragma unroll
    for (int ik = 0; ik < 2; ++ik) {
        f4 v4 = {pacc[ik][0], pacc[ik][1], pacc[ik][2], pacc[ik][3]};
        *reinterpret_cast<f4*>(pb + (size_t)(k0 + ik) * 64) = v4;
    }
}

// ---------------------------------------------------------------------------
// K2: grid 1024 (n = b>>4, 16-row l-chunk = b&15) x 256 threads, 4 blk/CU.
//   fc[l][e] = sum_k values[k,l,n] * P[n][k][e] + b[e]
//   M[l][e]  = LN_e(fc[l][:])  (+query residual const over e -> cancels)
//   broadcast M row to all 64 h slices: out[h][n][l][e].
// Compute is tiny (256 FMA/thread); the 268 MB nontemporal write stream
// dominates. Per wave per h: 1 KB fully contiguous stores.
// ---------------------------------------------------------------------------
__global__ __launch_bounds__(256) void fc_ln_bcast_kernel(
    const float* __restrict__ gv,
    const float* __restrict__ gbo,
    const float* __restrict__ glnw,
    const float* __restrict__ glnb,
    const float* __restrict__ wsP,
    float*       __restrict__ gout)
{
    __shared__ float PS[64 * 64];     // [k][e], 16 KB
    __shared__ float VnS[64 * 16];    // [k][l'], 4 KB

    const int t  = threadIdx.x;
    const int b  = blockIdx.x;
    const int n  = b >> 4;
    const int l0 = (b & 15) * 16;

    // stage P[n] (coalesced f4: 1024 f4, 4 per thread)
    const f4* psrc = reinterpret_cast<const f4*>(wsP + (size_t)n * 4096);
    #pragma unroll
    for (int i = 0; i < 4; ++i)
        reinterpret_cast<f4*>(PS)[t + 256 * i] = psrc[t + 256 * i];

    // stage VnS[k][l'] = values[k, l0+l', n]  (1024 scattered L2 reads)
    #pragma unroll
    for (int i = 0; i < 4; ++i) {
        int idx = t + 256 * i;
        int lp = idx & 15, k = idx >> 4;
        VnS[k * 16 + lp] =
            gv[(size_t)k * (L_SEQ * E_DIM) + (size_t)(l0 + lp) * E_DIM + n];
    }
    __syncthreads();

    const int tx = t & 15, ty = t >> 4;   // ty -> l' row, tx -> e-quad
    const int e0 = tx * 4;

    // fc[ty][e0:e0+4] = sum_k VnS[k][ty] * PS[k][e0:4]
    float fc0 = 0.f, fc1 = 0.f, fc2 = 0.f, fc3 = 0.f;
    #pragma unroll 8
    for (int k = 0; k < 64; ++k) {
        float v = VnS[k * 16 + ty];                      // LDS broadcast
        f4 p4 = *reinterpret_cast<const f4*>(&PS[k * 64 + e0]);
        fc0 = fmaf(v, p4[0], fc0);
        fc1 = fmaf(v, p4[1], fc1);
        fc2 = fmaf(v, p4[2], fc2);
        fc3 = fmaf(v, p4[3], fc3);
    }

    f4 be = *reinterpret_cast<const f4*>(&gbo[e0]);
    f4 lw = *reinterpret_cast<const f4*>(&glnw[e0]);
    f4 lb = *reinterpret_cast<const f4*>(&glnb[e0]);

    float v0 = fc0 + be[0];
    float v1 = fc1 + be[1];
    float v2 = fc2 + be[2];
    float v3 = fc3 + be[3];

    // LN over e: row ty spread across the 16 tx lanes (same wave)
    float s1 = (v0 + v1) + (v2 + v3);
    float s2 = (v0 * v0 + v1 * v1) + (v2 * v2 + v3 * v3);
    #pragma unroll
    for (int s = 1; s <= 8; s <<= 1) {
        s1 += __shfl_xor(s1, s);
        s2 += __shfl_xor(s2, s);
    }
    float mu  = s1 * (1.0f / 64.0f);
    float var = s2 * (1.0f / 64.0f) - mu * mu;
    float rs  = rsqrtf(var + LN_EPS);
    f4 o;
    o[0] = (v0 - mu) * rs * lw[0] + lb[0];
    o[1] = (v1 - mu) * rs * lw[1] + lb[1];
    o[2] = (v2 - mu) * rs * lw[2] + lb[2];
    o[3] = (v3 - mu) * rs * lw[3] + lb[3];

    // broadcast to all 64 h slices; per wave per h: 1 KB contiguous
    float* op = gout + (size_t)n * (L_SEQ * E_DIM)
                     + (size_t)(l0 + ty) * E_DIM + e0;
    const size_t hstride = (size_t)N_B * L_SEQ * E_DIM;  // 1,048,576 floats
    #pragma unroll 8
    for (int h = 0; h < 64; ++h) {
        __builtin_nontemporal_store(o, reinterpret_cast<f4*>(op));
        op += hstride;
    }
}

extern "C" void kernel_launch(void* const* d_in, const int* in_sizes, int n_in,
                              void* d_out, int out_size, void* d_ws, size_t ws_size,
                              hipStream_t stream)
{
    const float* gv  = (const float*)d_in[0];  // values  [N,L,E] f32
    const float* gk  = (const float*)d_in[1];  // keys    [N,L,E]
    const float* gq  = (const float*)d_in[2];  // query   [N,L,E]
    const float* gw  = (const float*)d_in[3];  // W_out   [E,E]
    const float* gbo = (const float*)d_in[4];  // b_out   [E]
    const float* glw = (const float*)d_in[5];  // ln_w    [E]
    const float* glb = (const float*)d_in[6];  // ln_b    [E]
    float* wsP = (float*)d_ws;                 // P: 64*64*64 f32 = 1 MiB
    float* out = (float*)d_out;                // [H,N,L,E] f32

    hipLaunchKernelGGL(attn_p_kernel, dim3(64), dim3(512), 0, stream,
                       gq, gk, gw, wsP);
    hipLaunchKernelGGL(fc_ln_bcast_kernel, dim3(1024), dim3(256), 0, stream,
                       gv, gbo, glw, glb, wsP, out);
}

// Round 3
// 304.946 us; speedup vs baseline: 1.0812x; 1.0212x over previous
//
#include <hip/hip_runtime.h>
#include <stdint.h>

#define L_SEQ 256
#define E_DIM 64
#define N_B   64
#define LN_EPS 1e-5f

typedef float f4 __attribute__((ext_vector_type(4)));

// ---------------------------------------------------------------------------
// K1: one block per n (grid 64 x 256 threads, 128 KB LDS).
//   energy[a,b] = sum_l Q[n,l,a]*K[n,l,b] ; attn = softmax over b (hd==1)
//   P[k][e]    = sum_q attn[q][k] * W_out[e][q]     (64^3 tiny GEMM)
//   wsP[n][k][e] = P                                 (1 MB total)
// 256 threads / 4x4 tiles: best LDS-instruction amortization (LDS-bound).
// ---------------------------------------------------------------------------
__global__ __launch_bounds__(256) void attn_p_kernel(
    const float* __restrict__ gq,
    const float* __restrict__ gk,
    const float* __restrict__ gw,
    float*       __restrict__ wsP)
{
    __shared__ float lds[32768];          // 128 KB
    float* Qs    = lds;                   // phase1: [l][a], 16384 floats
    float* Ks    = lds + 16384;           // phase1: [l][b], 16384 floats
    float* attnS = lds;                   // phase2: [q][k], 4096 (over Qs)
    float* WtS   = lds + 4096;            // phase2: [q][e] stride 68

    const int t = threadIdx.x;
    const int n = blockIdx.x;
    const float* qb = gq + (size_t)n * (L_SEQ * E_DIM);
    const float* kb = gk + (size_t)n * (L_SEQ * E_DIM);

    // ---- stage Q,K (coalesced f4): 4096 f4 per tile, 16 per thread ----
    #pragma unroll
    for (int i = 0; i < 16; ++i) {
        reinterpret_cast<f4*>(Qs)[t + 256 * i] =
            reinterpret_cast<const f4*>(qb)[t + 256 * i];
        reinterpret_cast<f4*>(Ks)[t + 256 * i] =
            reinterpret_cast<const f4*>(kb)[t + 256 * i];
    }
    __syncthreads();

    const int tx = t & 15, ty = t >> 4;   // tx -> b-tile, ty -> a-tile
    const int b0 = tx * 4, a0 = ty * 4;

    // ---- energy: 4x4 tile per thread (proven baseline code) ----
    float acc[4][4] = {};
    #pragma unroll 8
    for (int l = 0; l < L_SEQ; ++l) {
        f4 qa = *reinterpret_cast<const f4*>(&Qs[l * E_DIM + a0]);
        f4 kv = *reinterpret_cast<const f4*>(&Ks[l * E_DIM + b0]);
        #pragma unroll
        for (int ia = 0; ia < 4; ++ia)
            #pragma unroll
            for (int ib = 0; ib < 4; ++ib)
                acc[ia][ib] = fmaf(qa[ia], kv[ib], acc[ia][ib]);
    }

    // ---- softmax over b; row a0+ia spread over the 16 tx lanes ----
    #pragma unroll
    for (int ia = 0; ia < 4; ++ia) {
        float m = fmaxf(fmaxf(acc[ia][0], acc[ia][1]),
                        fmaxf(acc[ia][2], acc[ia][3]));
        #pragma unroll
        for (int s = 1; s <= 8; s <<= 1) m = fmaxf(m, __shfl_xor(m, s));
        float e0v = __expf(acc[ia][0] - m);
        float e1v = __expf(acc[ia][1] - m);
        float e2v = __expf(acc[ia][2] - m);
        float e3v = __expf(acc[ia][3] - m);
        float ssum = (e0v + e1v) + (e2v + e3v);
        #pragma unroll
        for (int s = 1; s <= 8; s <<= 1) ssum += __shfl_xor(ssum, s);
        float inv = 1.0f / ssum;
        acc[ia][0] = e0v * inv; acc[ia][1] = e1v * inv;
        acc[ia][2] = e2v * inv; acc[ia][3] = e3v * inv;
    }

    __syncthreads();   // all lanes done reading Qs/Ks before LDS reuse

    // ---- attnS[q][k] rows (f4), q = a0+ia ----
    #pragma unroll
    for (int ia = 0; ia < 4; ++ia) {
        f4 v4 = {acc[ia][0], acc[ia][1], acc[ia][2], acc[ia][3]};
        *reinterpret_cast<f4*>(&attnS[(a0 + ia) * 64 + b0]) = v4;
    }

    // ---- WtS[q][e] = W_out[e][q], stride 68 (rows 16B-aligned: 68*4=272) --
    #pragma unroll
    for (int i = 0; i < 16; ++i) {
        int idx = t + 256 * i;            // = e*64 + q
        WtS[(idx & 63) * 68 + (idx >> 6)] = gw[idx];
    }
    __syncthreads();

    // ---- P[k][e] = sum_q attn[q][k] * Wt[q][e]; 4k x 4e per thread ----
    const int k0 = ty * 4, e0 = tx * 4;
    float pacc[4][4] = {};
    #pragma unroll 8
    for (int q = 0; q < 64; ++q) {
        f4 av = *reinterpret_cast<const f4*>(&attnS[q * 64 + k0]);
        f4 wv = *reinterpret_cast<const f4*>(&WtS[q * 68 + e0]);
        #pragma unroll
        for (int ik = 0; ik < 4; ++ik)
            #pragma unroll
            for (int ie = 0; ie < 4; ++ie)
                pacc[ik][ie] = fmaf(av[ik], wv[ie], pacc[ik][ie]);
    }
    float* pb = wsP + (size_t)n * 4096 + e0;
    #pragma unroll
    for (int ik = 0; ik < 4; ++ik) {
        f4 v4 = {pacc[ik][0], pacc[ik][1], pacc[ik][2], pacc[ik][3]};
        *reinterpret_cast<f4*>(pb + (size_t)(k0 + ik) * 64) = v4;
    }
}

// ---------------------------------------------------------------------------
// K2: grid 1024 (n = b>>4, 16-row l-chunk = b&15) x 256 threads.
//   fc[l][e] = sum_k values[k,l,n] * P[n][k][e] + b[e]
//   ws2[n][l][e] = LN_e(fc[l][:])   (+query residual const over e -> cancels)
// Output is the 4 MB h-independent row tensor; ONE f4 store per thread.
// ---------------------------------------------------------------------------
__global__ __launch_bounds__(256) void fc_ln_kernel(
    const float* __restrict__ gv,
    const float* __restrict__ gbo,
    const float* __restrict__ glnw,
    const float* __restrict__ glnb,
    const float* __restrict__ wsP,
    float*       __restrict__ ws2)
{
    __shared__ float PS[64 * 64];     // [k][e], 16 KB
    __shared__ float VnS[64 * 16];    // [k][l'], 4 KB

    const int t  = threadIdx.x;
    const int b  = blockIdx.x;
    const int n  = b >> 4;
    const int l0 = (b & 15) * 16;

    // stage P[n] (coalesced f4: 1024 f4, 4 per thread)
    const f4* psrc = reinterpret_cast<const f4*>(wsP + (size_t)n * 4096);
    #pragma unroll
    for (int i = 0; i < 4; ++i)
        reinterpret_cast<f4*>(PS)[t + 256 * i] = psrc[t + 256 * i];

    // stage VnS[k][l'] = values[k, l0+l', n]  (scattered, L2/L3-resident)
    #pragma unroll
    for (int i = 0; i < 4; ++i) {
        int idx = t + 256 * i;
        int lp = idx & 15, k = idx >> 4;
        VnS[k * 16 + lp] =
            gv[(size_t)k * (L_SEQ * E_DIM) + (size_t)(l0 + lp) * E_DIM + n];
    }
    __syncthreads();

    const int tx = t & 15, ty = t >> 4;   // ty -> l' row, tx -> e-quad
    const int e0 = tx * 4;

    float fc0 = 0.f, fc1 = 0.f, fc2 = 0.f, fc3 = 0.f;
    #pragma unroll 8
    for (int k = 0; k < 64; ++k) {
        float v = VnS[k * 16 + ty];                      // LDS broadcast
        f4 p4 = *reinterpret_cast<const f4*>(&PS[k * 64 + e0]);
        fc0 = fmaf(v, p4[0], fc0);
        fc1 = fmaf(v, p4[1], fc1);
        fc2 = fmaf(v, p4[2], fc2);
        fc3 = fmaf(v, p4[3], fc3);
    }

    f4 be = *reinterpret_cast<const f4*>(&gbo[e0]);
    f4 lw = *reinterpret_cast<const f4*>(&glnw[e0]);
    f4 lb = *reinterpret_cast<const f4*>(&glnb[e0]);

    float v0 = fc0 + be[0];
    float v1 = fc1 + be[1];
    float v2 = fc2 + be[2];
    float v3 = fc3 + be[3];

    // LN over e: row ty spread across the 16 tx lanes (same wave)
    float s1 = (v0 + v1) + (v2 + v3);
    float s2 = (v0 * v0 + v1 * v1) + (v2 * v2 + v3 * v3);
    #pragma unroll
    for (int s = 1; s <= 8; s <<= 1) {
        s1 += __shfl_xor(s1, s);
        s2 += __shfl_xor(s2, s);
    }
    float mu  = s1 * (1.0f / 64.0f);
    float var = s2 * (1.0f / 64.0f) - mu * mu;
    float rs  = rsqrtf(var + LN_EPS);
    f4 o;
    o[0] = (v0 - mu) * rs * lw[0] + lb[0];
    o[1] = (v1 - mu) * rs * lw[1] + lb[1];
    o[2] = (v2 - mu) * rs * lw[2] + lb[2];
    o[3] = (v3 - mu) * rs * lw[3] + lb[3];

    *reinterpret_cast<f4*>(
        ws2 + (size_t)n * 16384 + (size_t)(l0 + ty) * 64 + e0) = o;
}

// ---------------------------------------------------------------------------
// K3: pure sequential broadcast. out[h] slice == ws2 verbatim (4 MB), so the
// broadcast is 64 independent memcpys. Block (h = b>>5, chunk c = b&31)
// streams a 128 KB fully-contiguous span: the same access pattern as the
// 6.4 TB/s fill kernel. Source is L2/L3-resident; with round-robin XCD
// dispatch all 64 h-copies of chunk c land on XCD (c % 8) -> L2 reuse.
// ---------------------------------------------------------------------------
__global__ __launch_bounds__(256) void bcast_kernel(
    const float* __restrict__ ws2,
    float*       __restrict__ gout)
{
    const int t = threadIdx.x;
    const int b = blockIdx.x;
    const int h = b >> 5;
    const int c = b & 31;

    const f4* src = reinterpret_cast<const f4*>(ws2) + (size_t)c * 8192;
    f4*       dst = reinterpret_cast<f4*>(gout)
                  + (size_t)h * 262144 + (size_t)c * 8192;

    #pragma unroll 8
    for (int i = 0; i < 32; ++i) {
        int idx = t + 256 * i;
        __builtin_nontemporal_store(src[idx], dst + idx);
    }
}

extern "C" void kernel_launch(void* const* d_in, const int* in_sizes, int n_in,
                              void* d_out, int out_size, void* d_ws, size_t ws_size,
                              hipStream_t stream)
{
    const float* gv  = (const float*)d_in[0];  // values  [N,L,E] f32
    const float* gk  = (const float*)d_in[1];  // keys    [N,L,E]
    const float* gq  = (const float*)d_in[2];  // query   [N,L,E]
    const float* gw  = (const float*)d_in[3];  // W_out   [E,E]
    const float* gbo = (const float*)d_in[4];  // b_out   [E]
    const float* glw = (const float*)d_in[5];  // ln_w    [E]
    const float* glb = (const float*)d_in[6];  // ln_b    [E]
    float* wsP = (float*)d_ws;                 // P:   64*64*64 f32 = 1 MiB
    float* ws2 = wsP + 262144;                 // row tensor: 4 MiB
    float* out = (float*)d_out;                // [H,N,L,E] f32

    hipLaunchKernelGGL(attn_p_kernel, dim3(64), dim3(256), 0, stream,
                       gq, gk, gw, wsP);
    hipLaunchKernelGGL(fc_ln_kernel, dim3(1024), dim3(256), 0, stream,
                       gv, gbo, glw, glb, wsP, ws2);
    hipLaunchKernelGGL(bcast_kernel, dim3(2048), dim3(256), 0, stream,
                       ws2, out);
}

// Round 4
// 299.906 us; speedup vs baseline: 1.0994x; 1.0168x over previous
//
#include <hip/hip_runtime.h>
#include <stdint.h>

#define L_SEQ 256
#define E_DIM 64
#define N_B   64
#define LN_EPS 1e-5f

typedef float f4 __attribute__((ext_vector_type(4)));

// ---------------------------------------------------------------------------
// K1: one block per n (grid 64 x 256 threads, 128 KB LDS).
//   energy[a,b] = sum_l Q[n,l,a]*K[n,l,b] ; attn = softmax over b (hd==1)
//   P[k][e]    = sum_q attn[q][k] * W_out[e][q]     (64^3 tiny GEMM)
//   wsP[n][k][e] = P                                 (1 MB total)
// ---------------------------------------------------------------------------
__global__ __launch_bounds__(256) void attn_p_kernel(
    const float* __restrict__ gq,
    const float* __restrict__ gk,
    const float* __restrict__ gw,
    float*       __restrict__ wsP)
{
    __shared__ float lds[32768];          // 128 KB
    float* Qs    = lds;                   // phase1: [l][a], 16384 floats
    float* Ks    = lds + 16384;           // phase1: [l][b], 16384 floats
    float* attnS = lds;                   // phase2: [q][k], 4096 (over Qs)
    float* WtS   = lds + 4096;            // phase2: [q][e] stride 68

    const int t = threadIdx.x;
    const int n = blockIdx.x;
    const float* qb = gq + (size_t)n * (L_SEQ * E_DIM);
    const float* kb = gk + (size_t)n * (L_SEQ * E_DIM);

    // ---- stage Q,K (coalesced f4): 4096 f4 per tile, 16 per thread ----
    #pragma unroll
    for (int i = 0; i < 16; ++i) {
        reinterpret_cast<f4*>(Qs)[t + 256 * i] =
            reinterpret_cast<const f4*>(qb)[t + 256 * i];
        reinterpret_cast<f4*>(Ks)[t + 256 * i] =
            reinterpret_cast<const f4*>(kb)[t + 256 * i];
    }
    __syncthreads();

    const int tx = t & 15, ty = t >> 4;   // tx -> b-tile, ty -> a-tile
    const int b0 = tx * 4, a0 = ty * 4;

    // ---- energy: 4x4 tile per thread (proven baseline code) ----
    float acc[4][4] = {};
    #pragma unroll 8
    for (int l = 0; l < L_SEQ; ++l) {
        f4 qa = *reinterpret_cast<const f4*>(&Qs[l * E_DIM + a0]);
        f4 kv = *reinterpret_cast<const f4*>(&Ks[l * E_DIM + b0]);
        #pragma unroll
        for (int ia = 0; ia < 4; ++ia)
            #pragma unroll
            for (int ib = 0; ib < 4; ++ib)
                acc[ia][ib] = fmaf(qa[ia], kv[ib], acc[ia][ib]);
    }

    // ---- softmax over b; row a0+ia spread over the 16 tx lanes ----
    #pragma unroll
    for (int ia = 0; ia < 4; ++ia) {
        float m = fmaxf(fmaxf(acc[ia][0], acc[ia][1]),
                        fmaxf(acc[ia][2], acc[ia][3]));
        #pragma unroll
        for (int s = 1; s <= 8; s <<= 1) m = fmaxf(m, __shfl_xor(m, s));
        float e0v = __expf(acc[ia][0] - m);
        float e1v = __expf(acc[ia][1] - m);
        float e2v = __expf(acc[ia][2] - m);
        float e3v = __expf(acc[ia][3] - m);
        float ssum = (e0v + e1v) + (e2v + e3v);
        #pragma unroll
        for (int s = 1; s <= 8; s <<= 1) ssum += __shfl_xor(ssum, s);
        float inv = 1.0f / ssum;
        acc[ia][0] = e0v * inv; acc[ia][1] = e1v * inv;
        acc[ia][2] = e2v * inv; acc[ia][3] = e3v * inv;
    }

    __syncthreads();   // all lanes done reading Qs/Ks before LDS reuse

    // ---- attnS[q][k] rows (f4), q = a0+ia ----
    #pragma unroll
    for (int ia = 0; ia < 4; ++ia) {
        f4 v4 = {acc[ia][0], acc[ia][1], acc[ia][2], acc[ia][3]};
        *reinterpret_cast<f4*>(&attnS[(a0 + ia) * 64 + b0]) = v4;
    }

    // ---- WtS[q][e] = W_out[e][q], stride 68 (rows 16B-aligned: 68*4=272) --
    #pragma unroll
    for (int i = 0; i < 16; ++i) {
        int idx = t + 256 * i;            // = e*64 + q
        WtS[(idx & 63) * 68 + (idx >> 6)] = gw[idx];
    }
    __syncthreads();

    // ---- P[k][e] = sum_q attn[q][k] * Wt[q][e]; 4k x 4e per thread ----
    const int k0 = ty * 4, e0 = tx * 4;
    float pacc[4][4] = {};
    #pragma unroll 8
    for (int q = 0; q < 64; ++q) {
        f4 av = *reinterpret_cast<const f4*>(&attnS[q * 64 + k0]);
        f4 wv = *reinterpret_cast<const f4*>(&WtS[q * 68 + e0]);
        #pragma unroll
        for (int ik = 0; ik < 4; ++ik)
            #pragma unroll
            for (int ie = 0; ie < 4; ++ie)
                pacc[ik][ie] = fmaf(av[ik], wv[ie], pacc[ik][ie]);
    }
    float* pb = wsP + (size_t)n * 4096 + e0;
    #pragma unroll
    for (int ik = 0; ik < 4; ++ik) {
        f4 v4 = {pacc[ik][0], pacc[ik][1], pacc[ik][2], pacc[ik][3]};
        *reinterpret_cast<f4*>(pb + (size_t)(k0 + ik) * 64) = v4;
    }
}

// ---------------------------------------------------------------------------
// K2: grid 1024 (n = b>>4, 16-row l-chunk = b&15) x 256 threads.
//   fc[l][e] = sum_k values[k,l,n] * P[n][k][e] + b[e]
//   ws2[n][l][e] = LN_e(fc[l][:])   (+query residual const over e -> cancels)
// ---------------------------------------------------------------------------
__global__ __launch_bounds__(256) void fc_ln_kernel(
    const float* __restrict__ gv,
    const float* __restrict__ gbo,
    const float* __restrict__ glnw,
    const float* __restrict__ glnb,
    const float* __restrict__ wsP,
    float*       __restrict__ ws2)
{
    __shared__ float PS[64 * 64];     // [k][e], 16 KB
    __shared__ float VnS[64 * 16];    // [k][l'], 4 KB

    const int t  = threadIdx.x;
    const int b  = blockIdx.x;
    const int n  = b >> 4;
    const int l0 = (b & 15) * 16;

    // stage P[n] (coalesced f4: 1024 f4, 4 per thread)
    const f4* psrc = reinterpret_cast<const f4*>(wsP + (size_t)n * 4096);
    #pragma unroll
    for (int i = 0; i < 4; ++i)
        reinterpret_cast<f4*>(PS)[t + 256 * i] = psrc[t + 256 * i];

    // stage VnS[k][l'] = values[k, l0+l', n]  (scattered, L2/L3-resident)
    #pragma unroll
    for (int i = 0; i < 4; ++i) {
        int idx = t + 256 * i;
        int lp = idx & 15, k = idx >> 4;
        VnS[k * 16 + lp] =
            gv[(size_t)k * (L_SEQ * E_DIM) + (size_t)(l0 + lp) * E_DIM + n];
    }
    __syncthreads();

    const int tx = t & 15, ty = t >> 4;   // ty -> l' row, tx -> e-quad
    const int e0 = tx * 4;

    float fc0 = 0.f, fc1 = 0.f, fc2 = 0.f, fc3 = 0.f;
    #pragma unroll 8
    for (int k = 0; k < 64; ++k) {
        float v = VnS[k * 16 + ty];                      // LDS broadcast
        f4 p4 = *reinterpret_cast<const f4*>(&PS[k * 64 + e0]);
        fc0 = fmaf(v, p4[0], fc0);
        fc1 = fmaf(v, p4[1], fc1);
        fc2 = fmaf(v, p4[2], fc2);
        fc3 = fmaf(v, p4[3], fc3);
    }

    f4 be = *reinterpret_cast<const f4*>(&gbo[e0]);
    f4 lw = *reinterpret_cast<const f4*>(&glnw[e0]);
    f4 lb = *reinterpret_cast<const f4*>(&glnb[e0]);

    float v0 = fc0 + be[0];
    float v1 = fc1 + be[1];
    float v2 = fc2 + be[2];
    float v3 = fc3 + be[3];

    // LN over e: row ty spread across the 16 tx lanes (same wave)
    float s1 = (v0 + v1) + (v2 + v3);
    float s2 = (v0 * v0 + v1 * v1) + (v2 * v2 + v3 * v3);
    #pragma unroll
    for (int s = 1; s <= 8; s <<= 1) {
        s1 += __shfl_xor(s1, s);
        s2 += __shfl_xor(s2, s);
    }
    float mu  = s1 * (1.0f / 64.0f);
    float var = s2 * (1.0f / 64.0f) - mu * mu;
    float rs  = rsqrtf(var + LN_EPS);
    f4 o;
    o[0] = (v0 - mu) * rs * lw[0] + lb[0];
    o[1] = (v1 - mu) * rs * lw[1] + lb[1];
    o[2] = (v2 - mu) * rs * lw[2] + lb[2];
    o[3] = (v3 - mu) * rs * lw[3] + lb[3];

    *reinterpret_cast<f4*>(
        ws2 + (size_t)n * 16384 + (size_t)(l0 + ty) * 64 + e0) = o;
}

// ---------------------------------------------------------------------------
// K3: pure broadcast, styled after the 6.4 TB/s rocclr fill kernel:
// PLAIN f4 stores (no nontemporal — NT bypasses L2 write aggregation and is
// the one writer attribute shared by every flat round so far), 4096 blocks
// x 16 f4/thread. Block (c = b>>6 source 64KB chunk, h = b&63): consecutive
// blocks share the source chunk, so each XCD's L2 fetches a chunk once for
// its 8 h-copies (32 MB total source traffic, L2/L3-resident).
// ---------------------------------------------------------------------------
__global__ __launch_bounds__(256) void bcast_kernel(
    const float* __restrict__ ws2,
    float*       __restrict__ gout)
{
    const int t = threadIdx.x;
    const int b = blockIdx.x;
    const int h = b & 63;
    const int c = b >> 6;

    const f4* src = reinterpret_cast<const f4*>(ws2) + (size_t)c * 4096;
    f4*       dst = reinterpret_cast<f4*>(gout)
                  + (size_t)h * 262144 + (size_t)c * 4096;

    #pragma unroll
    for (int i = 0; i < 16; ++i) {
        int idx = t + 256 * i;
        dst[idx] = src[idx];
    }
}

extern "C" void kernel_launch(void* const* d_in, const int* in_sizes, int n_in,
                              void* d_out, int out_size, void* d_ws, size_t ws_size,
                              hipStream_t stream)
{
    const float* gv  = (const float*)d_in[0];  // values  [N,L,E] f32
    const float* gk  = (const float*)d_in[1];  // keys    [N,L,E]
    const float* gq  = (const float*)d_in[2];  // query   [N,L,E]
    const float* gw  = (const float*)d_in[3];  // W_out   [E,E]
    const float* gbo = (const float*)d_in[4];  // b_out   [E]
    const float* glw = (const float*)d_in[5];  // ln_w    [E]
    const float* glb = (const float*)d_in[6];  // ln_b    [E]
    float* wsP = (float*)d_ws;                 // P:   64*64*64 f32 = 1 MiB
    float* ws2 = wsP + 262144;                 // row tensor: 4 MiB
    float* out = (float*)d_out;                // [H,N,L,E] f32

    hipLaunchKernelGGL(attn_p_kernel, dim3(64), dim3(256), 0, stream,
                       gq, gk, gw, wsP);
    hipLaunchKernelGGL(fc_ln_kernel, dim3(1024), dim3(256), 0, stream,
                       gv, gbo, glw, glb, wsP, ws2);
    hipLaunchKernelGGL(bcast_kernel, dim3(4096), dim3(256), 0, stream,
                       ws2, out);
}